// Round 7
// baseline (166.189 us; speedup 1.0000x reference)
//
#include <hip/hip_runtime.h>
#include <cmath>

#define FDIM 128

typedef __attribute__((ext_vector_type(8))) __bf16 bf16x8;
typedef __attribute__((ext_vector_type(4))) float f32x4;

// RNE f32 -> bf16 bits (cold paths)
__device__ inline unsigned short f2bf(float x) {
  unsigned int u = __float_as_uint(x);
  return (unsigned short)((u + 0x7FFFu + ((u >> 16) & 1u)) >> 16);
}
__device__ inline float bfw_lo(unsigned int w) { return __uint_as_float(w << 16); }
__device__ inline float bfw_hi(unsigned int w) { return __uint_as_float(w & 0xFFFF0000u); }

// Pack all three weight mats into bf16 MFMA B-fragment layout [ft][kt][lane][j].
// z=0: W1 [128][128] (8 ft), z=1: Wf [128][384] used cols, z=2: W2 [128][384] used cols.
__global__ __launch_bounds__(64) void pack_frag_kernel(
    const float* __restrict__ W1, const float* __restrict__ Wf, const float* __restrict__ W2,
    unsigned short* __restrict__ W1f, unsigned short* __restrict__ Wff,
    unsigned short* __restrict__ W2f) {
  const int ft = blockIdx.x, kt = blockIdx.y, z = blockIdx.z;
  const int lane = threadIdx.x;
  const float* W;
  unsigned short* out;
  int col, stride;
  if (z == 0) {
    if (ft >= 8) return;
    W = W1; out = W1f; col = ft * 16 + (lane & 15); stride = 128;
  } else {
    W = (z == 1) ? Wf : W2;
    out = (z == 1) ? Wff : W2f;
    col = 3 * ((ft & 7) * 16 + (lane & 15)) + 1 + (ft >> 3);
    stride = 384;
  }
  unsigned short g[8];
#pragma unroll
  for (int j = 0; j < 8; ++j) {
    const int k = kt * 32 + ((lane >> 4) << 3) + j;
    g[j] = f2bf(W[(size_t)k * stride + col]);
  }
  uint4 u;
  u.x = g[0] | ((unsigned int)g[1] << 16);
  u.y = g[2] | ((unsigned int)g[3] << 16);
  u.z = g[4] | ((unsigned int)g[5] << 16);
  u.w = g[6] | ((unsigned int)g[7] << 16);
  *(uint4*)&out[((size_t)(ft * 4 + kt) * 64 + lane) * 8] = u;
}

// phi = silu(h@W1+b1)@W2+b2 (used cols only), via two MFMA passes.
// 16 rows per block, 4 waves. Output: phiP[s][row][q] u32 packing
// (phi[fb*32+lcol], phi[fb*32+16+lcol]) with q = fb*16+lcol.
__global__ __launch_bounds__(256) void phi_mfma_kernel(
    const float* __restrict__ h, const float* __restrict__ b1, const float* __restrict__ b2,
    const unsigned short* __restrict__ W1f, const unsigned short* __restrict__ W2f,
    unsigned int* __restrict__ phiP, int BNA) {
  __shared__ __bf16 hA[4 * 64 * 8];           // 4 KB: h tile (16 rows), A-frag layout
  __shared__ unsigned short tS[16 * 128];     // 4 KB: t tile, swizzled row-major
  const int tid = threadIdx.x;
  const int lane = tid & 63;
  const int w = tid >> 6;       // 0..3
  const int hw = lane >> 4, lcol = lane & 15;
  const int r0 = blockIdx.x * 16;

  // stage h -> A-frag bf16 (one b128 group per thread)
  {
    const int gl = tid & 63;
    const int kt = tid >> 6;
    const int row = gl & 15;
    const int k0 = kt * 32 + ((gl >> 4) << 3);
    const int gr = r0 + row;
    bf16x8 v;
    if (gr < BNA) {
      const float4 f0 = *(const float4*)&h[(size_t)gr * FDIM + k0];
      const float4 f1 = *(const float4*)&h[(size_t)gr * FDIM + k0 + 4];
      v[0] = (__bf16)f0.x; v[1] = (__bf16)f0.y; v[2] = (__bf16)f0.z; v[3] = (__bf16)f0.w;
      v[4] = (__bf16)f1.x; v[5] = (__bf16)f1.y; v[6] = (__bf16)f1.z; v[7] = (__bf16)f1.w;
    } else {
#pragma unroll
      for (int j = 0; j < 8; ++j) v[j] = (__bf16)0.0f;
    }
    *reinterpret_cast<bf16x8*>(&hA[tid * 8]) = v;
  }

  // pass1 B-frags (W1): wave w -> f-cols [w*32, w*32+32)
  bf16x8 B1[2][4];
#pragma unroll
  for (int ftl = 0; ftl < 2; ++ftl)
#pragma unroll
    for (int kt = 0; kt < 4; ++kt)
      B1[ftl][kt] = *reinterpret_cast<const bf16x8*>(
          &W1f[(((size_t)(w * 2 + ftl) * 4 + kt) * 64 + lane) * 8]);
  float b1v[2];
#pragma unroll
  for (int ftl = 0; ftl < 2; ++ftl) b1v[ftl] = b1[w * 32 + ftl * 16 + lcol];
  __syncthreads();

  {
    bf16x8 ga[4];
#pragma unroll
    for (int kt = 0; kt < 4; ++kt)
      ga[kt] = *reinterpret_cast<const bf16x8*>(&hA[(kt * 64 + lane) * 8]);
    f32x4 acc[2];
    acc[0] = (f32x4){0.f, 0.f, 0.f, 0.f};
    acc[1] = (f32x4){0.f, 0.f, 0.f, 0.f};
#pragma unroll
    for (int ftl = 0; ftl < 2; ++ftl)
#pragma unroll
      for (int kt = 0; kt < 4; ++kt)
        acc[ftl] = __builtin_amdgcn_mfma_f32_16x16x32_bf16(ga[kt], B1[ftl][kt], acc[ftl], 0, 0, 0);
#pragma unroll
    for (int ftl = 0; ftl < 2; ++ftl)
#pragma unroll
      for (int reg = 0; reg < 4; ++reg) {
        const int row = hw * 4 + reg;
        const int fcol = w * 32 + ftl * 16 + lcol;
        const float x = acc[ftl][reg] + b1v[ftl];
        const float t = x / (1.0f + __expf(-x));
        const int byte = (row * 256 + fcol * 2) ^ ((row & 7) << 4);
        *(unsigned short*)((char*)tS + byte) = f2bf(t);
      }
  }

  // pass2 B-frags (W2 used cols): wave w -> 64 of 256 f'-cols
  bf16x8 B2[4][4];
#pragma unroll
  for (int ftl = 0; ftl < 4; ++ftl)
#pragma unroll
    for (int kt = 0; kt < 4; ++kt)
      B2[ftl][kt] = *reinterpret_cast<const bf16x8*>(
          &W2f[(((size_t)(w * 4 + ftl) * 4 + kt) * 64 + lane) * 8]);
  const int s = w >> 1;
  float blo[2], bhi[2];
#pragma unroll
  for (int p = 0; p < 2; ++p) {
    const int f_lo = (w & 1) * 64 + p * 32 + lcol;
    blo[p] = b2[3 * f_lo + 1 + s];
    bhi[p] = b2[3 * (f_lo + 16) + 1 + s];
  }
  __syncthreads();

  {
    bf16x8 ta[4];
#pragma unroll
    for (int kt = 0; kt < 4; ++kt) {
      const int row = lcol;
      const int k0 = kt * 32 + hw * 8;
      const int byte = (row * 256 + k0 * 2) ^ ((row & 7) << 4);
      ta[kt] = *reinterpret_cast<const bf16x8*>((const char*)tS + byte);
    }
    f32x4 acc[4];
#pragma unroll
    for (int ftl = 0; ftl < 4; ++ftl) acc[ftl] = (f32x4){0.f, 0.f, 0.f, 0.f};
#pragma unroll
    for (int ftl = 0; ftl < 4; ++ftl)
#pragma unroll
      for (int kt = 0; kt < 4; ++kt)
        acc[ftl] = __builtin_amdgcn_mfma_f32_16x16x32_bf16(ta[kt], B2[ftl][kt], acc[ftl], 0, 0, 0);
#pragma unroll
    for (int p = 0; p < 2; ++p)
#pragma unroll
      for (int reg = 0; reg < 4; ++reg) {
        const int row = hw * 4 + reg;
        const int gr = r0 + row;
        if (gr < BNA) {
          const float vlo = acc[2 * p][reg] + blo[p];
          const float vhi = acc[2 * p + 1][reg] + bhi[p];
          const unsigned int word = f2bf(vlo) | ((unsigned int)f2bf(vhi) << 16);
          phiP[(size_t)s * BNA * 64 + (size_t)gr * 64 + ((w & 1) * 2 + p) * 16 + lcol] = word;
        }
      }
  }
}

#define DLT  (5.0f / 127.0f)
#define DLT2 (DLT * DLT)
#define E2C  0.99690479f  /* exp(-2*DLT^2) */

// Main fused kernel: 512 threads = 8 waves, 128-atom tiles, 2 barriers/tile,
// lean registers (pf streamed per-sub). Wave w: split s=w>>2, f-block fb=w&3.
// Final cross-az reduction folded in via device-scope atomic ticket.
template <int ASPLIT>
__global__ __launch_bounds__(512, 4) void enc_main_kernel(
    const float* __restrict__ xyz, const float* __restrict__ cg_xyz,
    const unsigned short* __restrict__ Wff, const float* __restrict__ bf,
    const unsigned int* __restrict__ phiP, const float* __restrict__ Hc,
    float* __restrict__ pH, float* __restrict__ pV, int* __restrict__ cnt,
    float* __restrict__ out,
    int NA, int NC, int BNC, int BNA) {
  __shared__ __bf16 Gl[8 * 4 * 64 * 8];  // 32 KB A-frag layout, 128 atoms
  __shared__ float ul[128 * 3];
  __shared__ int ticket;

  const int az = blockIdx.x;
  const int c = blockIdx.y;
  const int b = blockIdx.z;
  const int bc = b * NC + c;
  const int tid = threadIdx.x;
  const int lane = tid & 63;
  const int w = tid >> 6;        // 0..7
  const int s = w >> 2;          // 0: dH, 1: dV
  const int fb = w & 3;          // 32-col f-block
  const int hw = lane >> 4, lcol = lane & 15;
  const size_t arow = (size_t)b * NA;

  const float cgx = cg_xyz[bc * 3 + 0];
  const float cgy = cg_xyz[bc * 3 + 1];
  const float cgz = cg_xyz[bc * 3 + 2];

  const int APA = (NA + ASPLIT - 1) / ASPLIT;
  const int a0 = az * APA;
  const int a_end = min(NA, a0 + APA);
  const int ntiles = (APA + 127) >> 7;

  // B fragments: ft = s*8 + fb*2 + ftl  (32 VGPR)
  bf16x8 Bf[2][4];
#pragma unroll
  for (int ftl = 0; ftl < 2; ++ftl)
#pragma unroll
    for (int kt = 0; kt < 4; ++kt)
      Bf[ftl][kt] = *reinterpret_cast<const bf16x8*>(
          &Wff[(((size_t)(s * 8 + fb * 2 + ftl) * 4 + kt) * 64 + lane) * 8]);

  float bfv[2];
#pragma unroll
  for (int ftl = 0; ftl < 2; ++ftl)
    bfv[ftl] = bf[3 * (fb * 32 + ftl * 16 + lcol) + 1 + s];

  const unsigned int* __restrict__ phiS = phiP + (size_t)s * BNA * 64;
  const int qoff = fb * 16 + lcol;

  float dHp[2] = {0.f, 0.f};
  float dVp[2][3] = {};

  // G-gen thread mapping: atom = tid&127, kq = tid>>7 (4 threads/atom, 32 k).
  const int ga_a = tid & 127;
  const int ga_kq = tid >> 7;

  for (int t = 0; t < ntiles; ++t) {
    const int abase = a0 + t * 128;
    __syncthreads();  // prev-tile MFMA/epilogue done reading Gl/ul

    // G generation: 4 chains of 8 (fresh exp pair each), self-computed dist.
    {
      const int a = abase + ga_a;
      float d, ux = 0.f, uy = 0.f, uz = 0.f;
      if (a < a_end) {
        const float dx = xyz[(arow + a) * 3 + 0] - cgx;
        const float dy = xyz[(arow + a) * 3 + 1] - cgy;
        const float dz = xyz[(arow + a) * 3 + 2] - cgz;
        d = sqrtf(dx * dx + dy * dy + dz * dz);
        const float inv = 1.0f / d;
        ux = dx * inv; uy = dy * inv; uz = dz * inv;
      } else {
        d = 40.0f;  // exp(-(40-o)^2) == 0 for all offsets
      }
      if (ga_kq == 0) {
        ul[ga_a * 3 + 0] = ux; ul[ga_a * 3 + 1] = uy; ul[ga_a * 3 + 2] = uz;
      }
      const int sub = ga_a >> 4;
      const int blk = (sub * 4 + ga_kq) * 64;
#pragma unroll
      for (int cc = 0; cc < 4; ++cc) {
        const int kb = ga_kq * 32 + cc * 8;
        const float d0 = d - (float)kb * DLT;
        float g = __expf(-d0 * d0);
        float r = __expf(2.0f * DLT * d - (float)(2 * kb + 1) * DLT2);
        bf16x8 gv;
#pragma unroll
        for (int j = 0; j < 8; ++j) {
          gv[j] = (__bf16)g;
          g *= r;
          r *= E2C;
        }
        *reinterpret_cast<bf16x8*>(&Gl[(blk + cc * 16 + (ga_a & 15)) * 8]) = gv;
      }
    }
    __syncthreads();

    // MFMA + fused epilogue, per 16-atom sub-tile; pf streamed 1-ahead.
    unsigned int pfA[4];
#pragma unroll
    for (int reg = 0; reg < 4; ++reg) {
      const int a = abase + hw * 4 + reg;
      pfA[reg] = (a < a_end) ? phiS[(arow + a) * 64 + qoff] : 0u;
    }
#pragma unroll
    for (int sub = 0; sub < 8; ++sub) {
      unsigned int pfB[4];
      if (sub + 1 < 8) {
#pragma unroll
        for (int reg = 0; reg < 4; ++reg) {
          const int a = abase + (sub + 1) * 16 + hw * 4 + reg;
          pfB[reg] = (a < a_end) ? phiS[(arow + a) * 64 + qoff] : 0u;
        }
      }
      bf16x8 ga[4];
#pragma unroll
      for (int kt = 0; kt < 4; ++kt)
        ga[kt] = *reinterpret_cast<const bf16x8*>(&Gl[((sub * 4 + kt) * 64 + lane) * 8]);
      f32x4 acc[2];
      acc[0] = (f32x4){0.f, 0.f, 0.f, 0.f};
      acc[1] = (f32x4){0.f, 0.f, 0.f, 0.f};
      __builtin_amdgcn_s_setprio(1);
#pragma unroll
      for (int ftl = 0; ftl < 2; ++ftl)
#pragma unroll
        for (int kt = 0; kt < 4; ++kt)
          acc[ftl] = __builtin_amdgcn_mfma_f32_16x16x32_bf16(ga[kt], Bf[ftl][kt], acc[ftl], 0, 0, 0);
      __builtin_amdgcn_s_setprio(0);
#pragma unroll
      for (int reg = 0; reg < 4; ++reg) {
        const int a_loc = sub * 16 + hw * 4 + reg;
        const unsigned int pw = pfA[reg];
        const float plo = bfw_lo(pw);
        const float phi_ = bfw_hi(pw);
        if (s == 0) {
          dHp[0] = fmaf(acc[0][reg] + bfv[0], plo, dHp[0]);
          dHp[1] = fmaf(acc[1][reg] + bfv[1], phi_, dHp[1]);
        } else {
          const float u0 = ul[a_loc * 3 + 0];
          const float u1 = ul[a_loc * 3 + 1];
          const float u2 = ul[a_loc * 3 + 2];
          const float t0 = (acc[0][reg] + bfv[0]) * plo;
          const float t1 = (acc[1][reg] + bfv[1]) * phi_;
          dVp[0][0] = fmaf(t0, u0, dVp[0][0]);
          dVp[0][1] = fmaf(t0, u1, dVp[0][1]);
          dVp[0][2] = fmaf(t0, u2, dVp[0][2]);
          dVp[1][0] = fmaf(t1, u0, dVp[1][0]);
          dVp[1][1] = fmaf(t1, u1, dVp[1][1]);
          dVp[1][2] = fmaf(t1, u2, dVp[1][2]);
        }
      }
#pragma unroll
      for (int reg = 0; reg < 4; ++reg) pfA[reg] = pfB[reg];
    }
  }

  // reduce across hw groups (lanes sharing lcol) and store partials
#pragma unroll
  for (int ftl = 0; ftl < 2; ++ftl) {
    const int f = fb * 32 + ftl * 16 + lcol;
    if (s == 0) {
      float v = dHp[ftl];
      v += __shfl_xor(v, 16);
      v += __shfl_xor(v, 32);
      if (lane < 16)
        pH[(size_t)(az * BNC + bc) * FDIM + f] = v;
    } else {
#pragma unroll
      for (int x = 0; x < 3; ++x) {
        float v = dVp[ftl][x];
        v += __shfl_xor(v, 16);
        v += __shfl_xor(v, 32);
        if (lane < 16)
          pV[((size_t)(az * BNC + bc) * FDIM + f) * 3 + x] = v;
      }
    }
  }

  // ---- folded final reduction: last az-block of this bc sums partials ----
  __threadfence();          // release this block's partial stores (device scope)
  __syncthreads();
  if (tid == 0) ticket = atomicAdd(&cnt[bc], 1);
  __syncthreads();
  if (ticket == ASPLIT - 1) {
    __threadfence();        // acquire: other blocks' partials now visible
    const int f = tid & 127;
    const int v = tid >> 7;  // 0: H, 1..3: V component v-1
    if (v == 0) {
      float sum = Hc[(size_t)bc * FDIM + f];
#pragma unroll
      for (int z = 0; z < ASPLIT; ++z) sum += pH[(size_t)(z * BNC + bc) * FDIM + f];
      out[(size_t)bc * FDIM + f] = sum;
    } else {
      const int x = v - 1;
      float sum = 0.f;
#pragma unroll
      for (int z = 0; z < ASPLIT; ++z)
        sum += pV[((size_t)(z * BNC + bc) * FDIM + f) * 3 + x];
      out[(size_t)BNC * FDIM + ((size_t)bc * FDIM + f) * 3 + x] = sum;
    }
  }
}

extern "C" void kernel_launch(void* const* d_in, const int* in_sizes, int n_in,
                              void* d_out, int out_size, void* d_ws, size_t ws_size,
                              hipStream_t stream) {
  // inputs: 0 assign(unused), 1 h, 2 H, 3 cg_xyz, 4 xyz, 5 cg_adj(unused),
  //         6 Wf, 7 bf, 8 W1, 9 b1, 10 W2, 11 b2
  const float* h      = (const float*)d_in[1];
  const float* Hc     = (const float*)d_in[2];
  const float* cg_xyz = (const float*)d_in[3];
  const float* xyz    = (const float*)d_in[4];
  const float* Wf     = (const float*)d_in[6];
  const float* bf     = (const float*)d_in[7];
  const float* W1     = (const float*)d_in[8];
  const float* b1     = (const float*)d_in[9];
  const float* W2     = (const float*)d_in[10];
  const float* b2     = (const float*)d_in[11];

  const int BNC = in_sizes[2] / FDIM;      // B*NC
  const int NC  = in_sizes[5] / BNC;       // cg_adj = B*NC*NC
  const int B   = BNC / NC;
  const int NA  = in_sizes[0] / B;
  const int BNA = B * NA;
  constexpr int ASPLIT = 4;

  // Workspace layout (bytes; W1f = 8*4*64*8 ushorts = 32768 B)
  char* wsb = (char*)d_ws;
  unsigned short* W1f = (unsigned short*)wsb;                        // 32768 B
  unsigned short* Wff = (unsigned short*)(wsb + 32768);              // 65536 B
  unsigned short* W2f = (unsigned short*)(wsb + 32768 + 65536);      // 65536 B
  unsigned int*  phiP = (unsigned int*)(wsb + 32768 + 2 * 65536);    // 2*BNA*64*4 B
  char* p = wsb + 32768 + 2 * 65536 + (size_t)2 * BNA * 64 * 4;
  float* pH = (float*)p;                   p += (size_t)ASPLIT * BNC * FDIM * 4;
  float* pV = (float*)p;                   p += (size_t)ASPLIT * BNC * FDIM * 3 * 4;
  int*  cnt = (int*)p;

  hipMemsetAsync(cnt, 0, BNC * sizeof(int), stream);
  pack_frag_kernel<<<dim3(16, 4, 3), 64, 0, stream>>>(W1, Wf, W2, W1f, Wff, W2f);
  phi_mfma_kernel<<<(BNA + 15) / 16, 256, 0, stream>>>(h, b1, b2, W1f, W2f, phiP, BNA);
  enc_main_kernel<ASPLIT><<<dim3(ASPLIT, NC, B), 512, 0, stream>>>(
      xyz, cg_xyz, Wff, bf, phiP, Hc, pH, pV, cnt, (float*)d_out, NA, NC, BNC, BNA);
}

// Round 8
// 40.708 us; speedup vs baseline: 4.0824x; 4.0824x over previous
//
#include <hip/hip_runtime.h>
#include <cmath>

#define FDIM 128

typedef __attribute__((ext_vector_type(8))) __bf16 bf16x8;
typedef __attribute__((ext_vector_type(4))) float f32x4;

// RNE f32 -> bf16 bits (cold paths)
__device__ inline unsigned short f2bf(float x) {
  unsigned int u = __float_as_uint(x);
  return (unsigned short)((u + 0x7FFFu + ((u >> 16) & 1u)) >> 16);
}
__device__ inline float bfw_lo(unsigned int w) { return __uint_as_float(w << 16); }
__device__ inline float bfw_hi(unsigned int w) { return __uint_as_float(w & 0xFFFF0000u); }

// Pack all three weight mats into bf16 MFMA B-fragment layout [ft][kt][lane][j].
// z=0: W1 [128][128] (8 ft), z=1: Wf [128][384] used cols, z=2: W2 [128][384] used cols.
__global__ __launch_bounds__(64) void pack_frag_kernel(
    const float* __restrict__ W1, const float* __restrict__ Wf, const float* __restrict__ W2,
    unsigned short* __restrict__ W1f, unsigned short* __restrict__ Wff,
    unsigned short* __restrict__ W2f) {
  const int ft = blockIdx.x, kt = blockIdx.y, z = blockIdx.z;
  const int lane = threadIdx.x;
  const float* W;
  unsigned short* out;
  int col, stride;
  if (z == 0) {
    if (ft >= 8) return;
    W = W1; out = W1f; col = ft * 16 + (lane & 15); stride = 128;
  } else {
    W = (z == 1) ? Wf : W2;
    out = (z == 1) ? Wff : W2f;
    col = 3 * ((ft & 7) * 16 + (lane & 15)) + 1 + (ft >> 3);
    stride = 384;
  }
  unsigned short g[8];
#pragma unroll
  for (int j = 0; j < 8; ++j) {
    const int k = kt * 32 + ((lane >> 4) << 3) + j;
    g[j] = f2bf(W[(size_t)k * stride + col]);
  }
  uint4 u;
  u.x = g[0] | ((unsigned int)g[1] << 16);
  u.y = g[2] | ((unsigned int)g[3] << 16);
  u.z = g[4] | ((unsigned int)g[5] << 16);
  u.w = g[6] | ((unsigned int)g[7] << 16);
  *(uint4*)&out[((size_t)(ft * 4 + kt) * 64 + lane) * 8] = u;
}

// phi = silu(h@W1+b1)@W2+b2 (used cols only), via two MFMA passes.
// 16 rows per block, 4 waves. Output: phiP[s][row][q] u32 packing
// (phi[fb*32+lcol], phi[fb*32+16+lcol]) with q = fb*16+lcol.
__global__ __launch_bounds__(256) void phi_mfma_kernel(
    const float* __restrict__ h, const float* __restrict__ b1, const float* __restrict__ b2,
    const unsigned short* __restrict__ W1f, const unsigned short* __restrict__ W2f,
    unsigned int* __restrict__ phiP, int BNA) {
  __shared__ __bf16 hA[4 * 64 * 8];           // 4 KB: h tile (16 rows), A-frag layout
  __shared__ unsigned short tS[16 * 128];     // 4 KB: t tile, swizzled row-major
  const int tid = threadIdx.x;
  const int lane = tid & 63;
  const int w = tid >> 6;       // 0..3
  const int hw = lane >> 4, lcol = lane & 15;
  const int r0 = blockIdx.x * 16;

  // stage h -> A-frag bf16 (one b128 group per thread)
  {
    const int gl = tid & 63;
    const int kt = tid >> 6;
    const int row = gl & 15;
    const int k0 = kt * 32 + ((gl >> 4) << 3);
    const int gr = r0 + row;
    bf16x8 v;
    if (gr < BNA) {
      const float4 f0 = *(const float4*)&h[(size_t)gr * FDIM + k0];
      const float4 f1 = *(const float4*)&h[(size_t)gr * FDIM + k0 + 4];
      v[0] = (__bf16)f0.x; v[1] = (__bf16)f0.y; v[2] = (__bf16)f0.z; v[3] = (__bf16)f0.w;
      v[4] = (__bf16)f1.x; v[5] = (__bf16)f1.y; v[6] = (__bf16)f1.z; v[7] = (__bf16)f1.w;
    } else {
#pragma unroll
      for (int j = 0; j < 8; ++j) v[j] = (__bf16)0.0f;
    }
    *reinterpret_cast<bf16x8*>(&hA[tid * 8]) = v;
  }

  // pass1 B-frags (W1): wave w -> f-cols [w*32, w*32+32)
  bf16x8 B1[2][4];
#pragma unroll
  for (int ftl = 0; ftl < 2; ++ftl)
#pragma unroll
    for (int kt = 0; kt < 4; ++kt)
      B1[ftl][kt] = *reinterpret_cast<const bf16x8*>(
          &W1f[(((size_t)(w * 2 + ftl) * 4 + kt) * 64 + lane) * 8]);
  float b1v[2];
#pragma unroll
  for (int ftl = 0; ftl < 2; ++ftl) b1v[ftl] = b1[w * 32 + ftl * 16 + lcol];
  __syncthreads();

  {
    bf16x8 ga[4];
#pragma unroll
    for (int kt = 0; kt < 4; ++kt)
      ga[kt] = *reinterpret_cast<const bf16x8*>(&hA[(kt * 64 + lane) * 8]);
    f32x4 acc[2];
    acc[0] = (f32x4){0.f, 0.f, 0.f, 0.f};
    acc[1] = (f32x4){0.f, 0.f, 0.f, 0.f};
#pragma unroll
    for (int ftl = 0; ftl < 2; ++ftl)
#pragma unroll
      for (int kt = 0; kt < 4; ++kt)
        acc[ftl] = __builtin_amdgcn_mfma_f32_16x16x32_bf16(ga[kt], B1[ftl][kt], acc[ftl], 0, 0, 0);
#pragma unroll
    for (int ftl = 0; ftl < 2; ++ftl)
#pragma unroll
      for (int reg = 0; reg < 4; ++reg) {
        const int row = hw * 4 + reg;
        const int fcol = w * 32 + ftl * 16 + lcol;
        const float x = acc[ftl][reg] + b1v[ftl];
        const float t = x / (1.0f + __expf(-x));
        const int byte = (row * 256 + fcol * 2) ^ ((row & 7) << 4);
        *(unsigned short*)((char*)tS + byte) = f2bf(t);
      }
  }

  // pass2 B-frags (W2 used cols): wave w -> 64 of 256 f'-cols
  bf16x8 B2[4][4];
#pragma unroll
  for (int ftl = 0; ftl < 4; ++ftl)
#pragma unroll
    for (int kt = 0; kt < 4; ++kt)
      B2[ftl][kt] = *reinterpret_cast<const bf16x8*>(
          &W2f[(((size_t)(w * 4 + ftl) * 4 + kt) * 64 + lane) * 8]);
  const int s = w >> 1;
  float blo[2], bhi[2];
#pragma unroll
  for (int p = 0; p < 2; ++p) {
    const int f_lo = (w & 1) * 64 + p * 32 + lcol;
    blo[p] = b2[3 * f_lo + 1 + s];
    bhi[p] = b2[3 * (f_lo + 16) + 1 + s];
  }
  __syncthreads();

  {
    bf16x8 ta[4];
#pragma unroll
    for (int kt = 0; kt < 4; ++kt) {
      const int row = lcol;
      const int k0 = kt * 32 + hw * 8;
      const int byte = (row * 256 + k0 * 2) ^ ((row & 7) << 4);
      ta[kt] = *reinterpret_cast<const bf16x8*>((const char*)tS + byte);
    }
    f32x4 acc[4];
#pragma unroll
    for (int ftl = 0; ftl < 4; ++ftl) acc[ftl] = (f32x4){0.f, 0.f, 0.f, 0.f};
#pragma unroll
    for (int ftl = 0; ftl < 4; ++ftl)
#pragma unroll
      for (int kt = 0; kt < 4; ++kt)
        acc[ftl] = __builtin_amdgcn_mfma_f32_16x16x32_bf16(ta[kt], B2[ftl][kt], acc[ftl], 0, 0, 0);
#pragma unroll
    for (int p = 0; p < 2; ++p)
#pragma unroll
      for (int reg = 0; reg < 4; ++reg) {
        const int row = hw * 4 + reg;
        const int gr = r0 + row;
        if (gr < BNA) {
          const float vlo = acc[2 * p][reg] + blo[p];
          const float vhi = acc[2 * p + 1][reg] + bhi[p];
          const unsigned int word = f2bf(vlo) | ((unsigned int)f2bf(vhi) << 16);
          phiP[(size_t)s * BNA * 64 + (size_t)gr * 64 + ((w & 1) * 2 + p) * 16 + lcol] = word;
        }
      }
  }
}

#define DLT  (5.0f / 127.0f)
#define DLT2 (DLT * DLT)
#define E2C  0.99690479f  /* exp(-2*DLT^2) */

// Main fused kernel: 512 threads = 8 waves, 128-atom tiles, 2 barriers/tile.
// Wave w: split s=w>>2, f-block fb=w&3 (32 f-cols). pf streamed 1-ahead.
// __launch_bounds__(512, 2): cap 256 VGPR -> no spills (R7's (512,4) cap of
// 128 spilled the persistent B-frags to scratch: VGPR_Count=52, 6x slowdown).
template <int ASPLIT>
__global__ __launch_bounds__(512, 2) void enc_main_kernel(
    const float* __restrict__ xyz, const float* __restrict__ cg_xyz,
    const unsigned short* __restrict__ Wff, const float* __restrict__ bf,
    const unsigned int* __restrict__ phiP,
    float* __restrict__ pH, float* __restrict__ pV,
    int NA, int NC, int BNC, int BNA) {
  __shared__ __bf16 Gl[8 * 4 * 64 * 8];  // 32 KB A-frag layout, 128 atoms
  __shared__ float ul[128 * 3];

  const int az = blockIdx.x;
  const int c = blockIdx.y;
  const int b = blockIdx.z;
  const int bc = b * NC + c;
  const int tid = threadIdx.x;
  const int lane = tid & 63;
  const int w = tid >> 6;        // 0..7
  const int s = w >> 2;          // 0: dH, 1: dV
  const int fb = w & 3;          // 32-col f-block
  const int hw = lane >> 4, lcol = lane & 15;
  const size_t arow = (size_t)b * NA;

  const float cgx = cg_xyz[bc * 3 + 0];
  const float cgy = cg_xyz[bc * 3 + 1];
  const float cgz = cg_xyz[bc * 3 + 2];

  const int APA = (NA + ASPLIT - 1) / ASPLIT;
  const int a0 = az * APA;
  const int a_end = min(NA, a0 + APA);
  const int ntiles = (APA + 127) >> 7;

  // B fragments: ft = s*8 + fb*2 + ftl  (32 VGPR, persistent)
  bf16x8 Bf[2][4];
#pragma unroll
  for (int ftl = 0; ftl < 2; ++ftl)
#pragma unroll
    for (int kt = 0; kt < 4; ++kt)
      Bf[ftl][kt] = *reinterpret_cast<const bf16x8*>(
          &Wff[(((size_t)(s * 8 + fb * 2 + ftl) * 4 + kt) * 64 + lane) * 8]);

  float bfv[2];
#pragma unroll
  for (int ftl = 0; ftl < 2; ++ftl)
    bfv[ftl] = bf[3 * (fb * 32 + ftl * 16 + lcol) + 1 + s];

  const unsigned int* __restrict__ phiS = phiP + (size_t)s * BNA * 64;
  const int qoff = fb * 16 + lcol;

  float dHp[2] = {0.f, 0.f};
  float dVp[2][3] = {};

  // G-gen thread mapping: atom = tid&127, kq = tid>>7 (4 threads/atom, 32 k).
  const int ga_a = tid & 127;
  const int ga_kq = tid >> 7;

  for (int t = 0; t < ntiles; ++t) {
    const int abase = a0 + t * 128;
    __syncthreads();  // prev-tile MFMA/epilogue done reading Gl/ul

    // G generation: 4 chains of 8 (fresh exp pair each), self-computed dist.
    {
      const int a = abase + ga_a;
      float d, ux = 0.f, uy = 0.f, uz = 0.f;
      if (a < a_end) {
        const float dx = xyz[(arow + a) * 3 + 0] - cgx;
        const float dy = xyz[(arow + a) * 3 + 1] - cgy;
        const float dz = xyz[(arow + a) * 3 + 2] - cgz;
        d = sqrtf(dx * dx + dy * dy + dz * dz);
        const float inv = 1.0f / d;
        ux = dx * inv; uy = dy * inv; uz = dz * inv;
      } else {
        d = 40.0f;  // exp(-(40-o)^2) == 0 for all offsets
      }
      if (ga_kq == 0) {
        ul[ga_a * 3 + 0] = ux; ul[ga_a * 3 + 1] = uy; ul[ga_a * 3 + 2] = uz;
      }
      const int sub = ga_a >> 4;
      const int blk = (sub * 4 + ga_kq) * 64;
#pragma unroll
      for (int cc = 0; cc < 4; ++cc) {
        const int kb = ga_kq * 32 + cc * 8;
        const float d0 = d - (float)kb * DLT;
        float g = __expf(-d0 * d0);
        float r = __expf(2.0f * DLT * d - (float)(2 * kb + 1) * DLT2);
        bf16x8 gv;
#pragma unroll
        for (int j = 0; j < 8; ++j) {
          gv[j] = (__bf16)g;
          g *= r;
          r *= E2C;
        }
        *reinterpret_cast<bf16x8*>(&Gl[(blk + cc * 16 + (ga_a & 15)) * 8]) = gv;
      }
    }
    __syncthreads();

    // MFMA + fused epilogue, per 16-atom sub-tile; pf streamed 1-ahead.
    unsigned int pfA[4];
#pragma unroll
    for (int reg = 0; reg < 4; ++reg) {
      const int a = abase + hw * 4 + reg;
      pfA[reg] = (a < a_end) ? phiS[(arow + a) * 64 + qoff] : 0u;
    }
#pragma unroll
    for (int sub = 0; sub < 8; ++sub) {
      unsigned int pfB[4];
      if (sub + 1 < 8) {
#pragma unroll
        for (int reg = 0; reg < 4; ++reg) {
          const int a = abase + (sub + 1) * 16 + hw * 4 + reg;
          pfB[reg] = (a < a_end) ? phiS[(arow + a) * 64 + qoff] : 0u;
        }
      }
      bf16x8 ga[4];
#pragma unroll
      for (int kt = 0; kt < 4; ++kt)
        ga[kt] = *reinterpret_cast<const bf16x8*>(&Gl[((sub * 4 + kt) * 64 + lane) * 8]);
      f32x4 acc[2];
      acc[0] = (f32x4){0.f, 0.f, 0.f, 0.f};
      acc[1] = (f32x4){0.f, 0.f, 0.f, 0.f};
      __builtin_amdgcn_s_setprio(1);
#pragma unroll
      for (int ftl = 0; ftl < 2; ++ftl)
#pragma unroll
        for (int kt = 0; kt < 4; ++kt)
          acc[ftl] = __builtin_amdgcn_mfma_f32_16x16x32_bf16(ga[kt], Bf[ftl][kt], acc[ftl], 0, 0, 0);
      __builtin_amdgcn_s_setprio(0);
#pragma unroll
      for (int reg = 0; reg < 4; ++reg) {
        const int a_loc = sub * 16 + hw * 4 + reg;
        const unsigned int pw = pfA[reg];
        const float plo = bfw_lo(pw);
        const float phi_ = bfw_hi(pw);
        if (s == 0) {
          dHp[0] = fmaf(acc[0][reg] + bfv[0], plo, dHp[0]);
          dHp[1] = fmaf(acc[1][reg] + bfv[1], phi_, dHp[1]);
        } else {
          const float u0 = ul[a_loc * 3 + 0];
          const float u1 = ul[a_loc * 3 + 1];
          const float u2 = ul[a_loc * 3 + 2];
          const float t0 = (acc[0][reg] + bfv[0]) * plo;
          const float t1 = (acc[1][reg] + bfv[1]) * phi_;
          dVp[0][0] = fmaf(t0, u0, dVp[0][0]);
          dVp[0][1] = fmaf(t0, u1, dVp[0][1]);
          dVp[0][2] = fmaf(t0, u2, dVp[0][2]);
          dVp[1][0] = fmaf(t1, u0, dVp[1][0]);
          dVp[1][1] = fmaf(t1, u1, dVp[1][1]);
          dVp[1][2] = fmaf(t1, u2, dVp[1][2]);
        }
      }
#pragma unroll
      for (int reg = 0; reg < 4; ++reg) pfA[reg] = pfB[reg];
    }
  }

  // reduce across hw groups (lanes sharing lcol) and store partials
#pragma unroll
  for (int ftl = 0; ftl < 2; ++ftl) {
    const int f = fb * 32 + ftl * 16 + lcol;
    if (s == 0) {
      float v = dHp[ftl];
      v += __shfl_xor(v, 16);
      v += __shfl_xor(v, 32);
      if (lane < 16)
        pH[(size_t)(az * BNC + bc) * FDIM + f] = v;
    } else {
#pragma unroll
      for (int x = 0; x < 3; ++x) {
        float v = dVp[ftl][x];
        v += __shfl_xor(v, 16);
        v += __shfl_xor(v, 32);
        if (lane < 16)
          pV[((size_t)(az * BNC + bc) * FDIM + f) * 3 + x] = v;
      }
    }
  }
}

template <int ASPLIT>
__global__ __launch_bounds__(FDIM) void reduce_kernel(
    const float* __restrict__ H, const float* __restrict__ pH, const float* __restrict__ pV,
    float* __restrict__ out, int BNC) {
  const int bc = blockIdx.x;
  const int f = threadIdx.x;
  float s = H[(size_t)bc * FDIM + f];
#pragma unroll
  for (int az = 0; az < ASPLIT; ++az) s += pH[(size_t)(az * BNC + bc) * FDIM + f];
  out[(size_t)bc * FDIM + f] = s;
  float* outV = out + (size_t)BNC * FDIM;
#pragma unroll
  for (int x = 0; x < 3; ++x) {
    float v = 0.f;
#pragma unroll
    for (int az = 0; az < ASPLIT; ++az) v += pV[((size_t)(az * BNC + bc) * FDIM + f) * 3 + x];
    outV[((size_t)bc * FDIM + f) * 3 + x] = v;
  }
}

extern "C" void kernel_launch(void* const* d_in, const int* in_sizes, int n_in,
                              void* d_out, int out_size, void* d_ws, size_t ws_size,
                              hipStream_t stream) {
  // inputs: 0 assign(unused), 1 h, 2 H, 3 cg_xyz, 4 xyz, 5 cg_adj(unused),
  //         6 Wf, 7 bf, 8 W1, 9 b1, 10 W2, 11 b2
  const float* h      = (const float*)d_in[1];
  const float* Hc     = (const float*)d_in[2];
  const float* cg_xyz = (const float*)d_in[3];
  const float* xyz    = (const float*)d_in[4];
  const float* Wf     = (const float*)d_in[6];
  const float* bf     = (const float*)d_in[7];
  const float* W1     = (const float*)d_in[8];
  const float* b1     = (const float*)d_in[9];
  const float* W2     = (const float*)d_in[10];
  const float* b2     = (const float*)d_in[11];

  const int BNC = in_sizes[2] / FDIM;      // B*NC
  const int NC  = in_sizes[5] / BNC;       // cg_adj = B*NC*NC
  const int B   = BNC / NC;
  const int NA  = in_sizes[0] / B;
  const int BNA = B * NA;
  constexpr int ASPLIT = 4;

  // Workspace layout (bytes; W1f = 8*4*64*8 ushorts = 32768 B)
  char* wsb = (char*)d_ws;
  unsigned short* W1f = (unsigned short*)wsb;                        // 32768 B
  unsigned short* Wff = (unsigned short*)(wsb + 32768);              // 65536 B
  unsigned short* W2f = (unsigned short*)(wsb + 32768 + 65536);      // 65536 B
  unsigned int*  phiP = (unsigned int*)(wsb + 32768 + 2 * 65536);    // 2*BNA*64*4 B
  char* p = wsb + 32768 + 2 * 65536 + (size_t)2 * BNA * 64 * 4;
  float* pH = (float*)p;                   p += (size_t)ASPLIT * BNC * FDIM * 4;
  float* pV = (float*)p;

  pack_frag_kernel<<<dim3(16, 4, 3), 64, 0, stream>>>(W1, Wf, W2, W1f, Wff, W2f);
  phi_mfma_kernel<<<(BNA + 15) / 16, 256, 0, stream>>>(h, b1, b2, W1f, W2f, phiP, BNA);
  enc_main_kernel<ASPLIT><<<dim3(ASPLIT, NC, B), 512, 0, stream>>>(
      xyz, cg_xyz, Wff, bf, phiP, pH, pV, NA, NC, BNC, BNA);
  reduce_kernel<ASPLIT><<<BNC, FDIM, 0, stream>>>(Hc, pH, pV, (float*)d_out, BNC);
}